// Round 2
// baseline (265.458 us; speedup 1.0000x reference)
//
#include <hip/hip_runtime.h>
#include <math.h>

// LinearGating: B=4,S=4096,D=2048,E=64,K=2 -> N=16384 rows
// out layout (flat float32): [weights N*64][indices N*2 (as float)][logits N*64][probs N*64]
//
// Structure: 256 blocks x 512 threads (8 waves). Each wave = 64 rows (1 row/lane)
// x a fixed 8-expert slice => W addresses are wave-uniform => SGPR loads,
// FMA form v_fma_f32 acc, s_w, v_x. LDS only holds the x tile (0.25 B/FMA).

constexpr int NROWS = 16384;
constexpr int DDIM  = 2048;
constexpr int NE    = 64;
constexpr int BM    = 64;             // rows per block (= lanes per wave)
constexpr int BK    = 64;             // k tile
constexpr int NKT   = DDIM / BK;      // 32
constexpr int XST   = 68;             // x tile stride: 68 floats -> 17-dword lane walk
                                      // (17 coprime 32 => conflict-free) and 272 B row
                                      // stride => 16 B aligned float4
constexpr float NSCALE = 1.0f / (64.0f * 64.0f);

__device__ inline float softplus_f(float x) {
    // matches jax.nn.softplus: max(x,0) + log1p(exp(-|x|))
    return fmaxf(x, 0.0f) + log1pf(expf(-fabsf(x)));
}

__global__ __launch_bounds__(512) void gating_kernel(
    const float* __restrict__ x, const float* __restrict__ Wg,
    const float* __restrict__ Wn, const float* __restrict__ noise,
    float* __restrict__ out_w, float* __restrict__ out_idx,
    float* __restrict__ out_logits, float* __restrict__ out_probs)
{
    __shared__ float smem[2 * BM * XST];   // 2 x 17408 B = 34816 B; epilogue reuses it

    const int tid  = threadIdx.x;
    const int lane = tid & 63;                                    // = row within block
    const int wv   = __builtin_amdgcn_readfirstlane(tid >> 6);    // wave id 0..7 (SGPR)
    const int e0   = wv * 8;                                      // expert slice base
    const int row0 = blockIdx.x * BM;

    float accg[8], accn[8];
    #pragma unroll
    for (int j = 0; j < 8; ++j) { accg[j] = 0.0f; accn[j] = 0.0f; }

    // --- staging assignment: 512 threads x 2 float4 = 16 KB tile ---
    const int sr  = tid >> 4;           // 0..31  (rows sr and sr+32)
    const int skq = (tid & 15) * 4;     // 0..60
    const float* xbase = x + (size_t)row0 * DDIM;

    // prologue: load + write tile 0
    float4 st0 = *reinterpret_cast<const float4*>(xbase + (size_t)sr * DDIM + skq);
    float4 st1 = *reinterpret_cast<const float4*>(xbase + (size_t)(sr + 32) * DDIM + skq);
    *reinterpret_cast<float4*>(smem + sr * XST + skq)        = st0;
    *reinterpret_cast<float4*>(smem + (sr + 32) * XST + skq) = st1;

    int cur = 0;
    for (int kt = 0; kt < NKT; ++kt) {
        if (kt + 1 < NKT) {   // issue next tile's global loads early
            const float* src = xbase + (size_t)(kt + 1) * BK + skq;
            st0 = *reinterpret_cast<const float4*>(src + (size_t)sr * DDIM);
            st1 = *reinterpret_cast<const float4*>(src + (size_t)(sr + 32) * DDIM);
        }
        __syncthreads();   // buf[cur] writes visible; prev readers of buf[cur^1] done

        const float* xb = smem + cur * BM * XST;
        const float* wg_base = Wg + (size_t)kt * BK * NE + e0;   // wave-uniform
        const float* wn_base = Wn + (size_t)kt * BK * NE + e0;

        #pragma unroll 2
        for (int kk = 0; kk < BK; kk += 4) {
            float4 xv = *reinterpret_cast<const float4*>(xb + lane * XST + kk);
            float xa[4] = {xv.x, xv.y, xv.z, xv.w};
            #pragma unroll
            for (int q = 0; q < 4; ++q) {
                const float* wg = wg_base + (size_t)(kk + q) * NE;  // uniform -> s_load
                const float* wn = wn_base + (size_t)(kk + q) * NE;
                #pragma unroll
                for (int j = 0; j < 8; ++j) {
                    accg[j] = fmaf(xa[q], wg[j], accg[j]);
                    accn[j] = fmaf(xa[q], wn[j], accn[j]);
                }
            }
        }

        if (kt + 1 < NKT) {   // write next tile into the other buffer
            float* nb = smem + (cur ^ 1) * BM * XST;
            *reinterpret_cast<float4*>(nb + sr * XST + skq)        = st0;
            *reinterpret_cast<float4*>(nb + (sr + 32) * XST + skq) = st1;
        }
        cur ^= 1;
    }

    // ================= epilogue =================
    const int n = row0 + lane;
    float4 nz0 = *reinterpret_cast<const float4*>(noise + (size_t)n * NE + e0);
    float4 nz1 = *reinterpret_cast<const float4*>(noise + (size_t)n * NE + e0 + 4);
    float nzv[8] = {nz0.x, nz0.y, nz0.z, nz0.w, nz1.x, nz1.y, nz1.z, nz1.w};

    float lv[8];
    #pragma unroll
    for (int j = 0; j < 8; ++j) {
        float nstd = softplus_f(accn[j]) * NSCALE;
        lv[j] = accg[j] + nzv[j] * nstd;
    }
    // coalesced logits store (e0 multiple of 8 -> 16B aligned)
    *reinterpret_cast<float4*>(out_logits + (size_t)n * NE + e0)     = make_float4(lv[0], lv[1], lv[2], lv[3]);
    *reinterpret_cast<float4*>(out_logits + (size_t)n * NE + e0 + 4) = make_float4(lv[4], lv[5], lv[6], lv[7]);

    __syncthreads();   // all waves done reading x tiles -> smem reusable
    float* lg = smem;  // [64][65]
    #pragma unroll
    for (int j = 0; j < 8; ++j) lg[lane * 65 + e0 + j] = lv[j];
    __syncthreads();

    // remap: wave wv handles rows wv*8 .. wv*8+7, 8 lanes per row
    const int g = lane >> 3;           // row within wave's group
    const int c = lane & 7;            // expert chunk
    const int row2 = wv * 8 + g;
    const int n2 = row0 + row2;

    float mv[8];
    #pragma unroll
    for (int j = 0; j < 8; ++j) mv[j] = lg[row2 * 65 + c * 8 + j];

    // local top-2 over this lane's 8 experts
    float v0 = -INFINITY, v1 = -INFINITY;
    int i0 = 0, i1 = 0;
    #pragma unroll
    for (int j = 0; j < 8; ++j) {
        float v = mv[j]; int e = c * 8 + j;
        if (v > v0) { v1 = v0; i1 = i0; v0 = v; i0 = e; }
        else if (v > v1) { v1 = v; i1 = e; }
    }
    // merge across the 8 lanes of this row
    #pragma unroll
    for (int m = 1; m <= 4; m <<= 1) {
        float ov0 = __shfl_xor(v0, m), ov1 = __shfl_xor(v1, m);
        int   oi0 = __shfl_xor(i0, m), oi1 = __shfl_xor(i1, m);
        if (ov0 > v0) {
            bool keep = (v0 > ov1);
            v1 = keep ? v0 : ov1; i1 = keep ? i0 : oi1;
            v0 = ov0; i0 = oi0;
        } else if (ov0 > v1) {
            v1 = ov0; i1 = oi0;
        }
    }
    // enforce group-consistent result (broadcast from group leader lane)
    const int src = lane & 56;
    v0 = __shfl(v0, src); i0 = __shfl(i0, src);
    v1 = __shfl(v1, src); i1 = __shfl(i1, src);

    // softmax denominator over all 64 experts
    float se = 0.0f;
    #pragma unroll
    for (int j = 0; j < 8; ++j) se += expf(mv[j] - v0);
    se += __shfl_xor(se, 1); se += __shfl_xor(se, 2); se += __shfl_xor(se, 4);
    float inv_se = 1.0f / se;

    float t  = expf(v1 - v0);
    float w0 = 1.0f / (1.0f + t);
    float w1 = t * w0;

    float pr[8], wt[8];
    #pragma unroll
    for (int j = 0; j < 8; ++j) {
        int e = c * 8 + j;
        pr[j] = expf(mv[j] - v0) * inv_se;
        wt[j] = (e == i0) ? w0 : ((e == i1) ? w1 : 0.0f);
    }
    *reinterpret_cast<float4*>(out_probs + (size_t)n2 * NE + c * 8)     = make_float4(pr[0], pr[1], pr[2], pr[3]);
    *reinterpret_cast<float4*>(out_probs + (size_t)n2 * NE + c * 8 + 4) = make_float4(pr[4], pr[5], pr[6], pr[7]);
    *reinterpret_cast<float4*>(out_w + (size_t)n2 * NE + c * 8)         = make_float4(wt[0], wt[1], wt[2], wt[3]);
    *reinterpret_cast<float4*>(out_w + (size_t)n2 * NE + c * 8 + 4)     = make_float4(wt[4], wt[5], wt[6], wt[7]);
    if (c == 0) {
        out_idx[(size_t)n2 * 2]     = (float)i0;
        out_idx[(size_t)n2 * 2 + 1] = (float)i1;
    }
}

extern "C" void kernel_launch(void* const* d_in, const int* in_sizes, int n_in,
                              void* d_out, int out_size, void* d_ws, size_t ws_size,
                              hipStream_t stream) {
    (void)in_sizes; (void)n_in; (void)d_ws; (void)ws_size; (void)out_size;
    const float* x     = (const float*)d_in[0];
    const float* Wg    = (const float*)d_in[1];
    const float* Wn    = (const float*)d_in[2];
    const float* noise = (const float*)d_in[3];
    float* out        = (float*)d_out;
    float* out_w      = out;                                  // N*64
    float* out_idx    = out + (size_t)NROWS * NE;             // N*2
    float* out_logits = out_idx + (size_t)NROWS * 2;          // N*64
    float* out_probs  = out_logits + (size_t)NROWS * NE;      // N*64

    dim3 grid(NROWS / BM);   // 256 blocks, 1 per CU
    gating_kernel<<<grid, 512, 0, stream>>>(x, Wg, Wn, noise,
                                            out_w, out_idx, out_logits, out_probs);
}

// Round 4
// 79.981 us; speedup vs baseline: 3.3190x; 3.3190x over previous
//
#include <hip/hip_runtime.h>
#include <math.h>

// LinearGating: B=4,S=4096,D=2048,E=64,K=2 -> N=16384 rows
// out (flat f32): [weights N*64][indices N*2 (as float)][logits N*64][probs N*64]
//
// fp16 split-3 MFMA GEMM: C[N x 128] = X[N x 2048] @ [Wg|Wn]
//   x = h + d, w = H + D (h,H fp16 high parts; d,D residuals)
//   acc1 += h*H ; acc2 += h*(D*2^6) + (d*2^6)*H ; C = acc1 + acc2*2^-6
// wprep: W -> fragment-ordered fp16 blobs {H, D*2^6} in ws (1 MB)
// main : 256 blocks x 256 thr = 4 waves, each wave = 64 rows x 32 cols,
//        full K per wave (no k-split), 48KB static LDS double-buffer,
//        fused epilogue (noise inject, top-2, masked softmax, full softmax).

typedef _Float16 f16;
typedef f16  f16x8  __attribute__((ext_vector_type(8)));
typedef float f32x16 __attribute__((ext_vector_type(16)));

constexpr int NROWS = 16384;
constexpr int DDIM  = 2048;
constexpr int NE    = 64;
constexpr int BM    = 64;
constexpr int KI    = 32;            // k per iteration
constexpr int NITER = DDIM / KI;     // 64
constexpr float NSCALE = 1.0f / 4096.0f;

__device__ __forceinline__ float softplus_f(float x) {
    return fmaxf(x, 0.0f) + log1pf(expf(-fabsf(x)));
}

// LDS blob offsets (1KB blobs = 64 lanes x 16B, lane-linear)
// A: [0, 16K)   buf(2) x v(2) x m(2) x s(2)
// B: [16K, 48K) buf(2) x v(2) x f(4) x s(2)
__device__ __forceinline__ int a_off(int buf, int v, int m, int s) {
    return (((buf * 2 + v) * 2 + m) * 2 + s) * 1024;
}
__device__ __forceinline__ int b_off(int buf, int v, int f, int s) {
    return 16384 + (((buf * 2 + v) * 4 + f) * 2 + s) * 1024;
}

__device__ __forceinline__ void gload_lds16(const void* g, void* l) {
    __builtin_amdgcn_global_load_lds(
        (const __attribute__((address_space(1))) void*)g,
        (__attribute__((address_space(3))) void*)l, 16, 0, 0);
}

// ---------------- W prep: fragment-ordered fp16 {H, D*2^6} ----------------
// blob(S 0..127, f 0..3, v 0..1): lane l, elem j = Wcat[S*16+(l>>5)*8+j][f*32+(l&31)]
// (Wcat = [Wg | Wn], 2048 x 128)
__global__ __launch_bounds__(256) void wprep_kernel(
    const float* __restrict__ Wg, const float* __restrict__ Wn,
    f16* __restrict__ ws)
{
    int t = blockIdx.x * 256 + threadIdx.x;    // 0..32767
    int S = t >> 8;
    int f = (t >> 6) & 3;
    int l = t & 63;
    int k0  = S * 16 + (l >> 5) * 8;
    int col = f * 32 + (l & 31);
    const float* src = (col < NE) ? (Wg + col) : (Wn + col - NE);
    f16x8 hp, lp;
    #pragma unroll
    for (int j = 0; j < 8; ++j) {
        float w  = src[(size_t)(k0 + j) * NE];
        f16 h    = (f16)w;
        float hf = (float)h;
        hp[j] = h;
        lp[j] = (f16)((w - hf) * 64.0f);
    }
    size_t base = (size_t)(S * 4 + f) * 1024;   // f16 units; v=0 then v=1
    *(f16x8*)(ws + base + l * 8)       = hp;
    *(f16x8*)(ws + base + 512 + l * 8) = lp;
}

// ---------------- main fused kernel ----------------
__global__ __launch_bounds__(256, 1) void gemm_gating(
    const float* __restrict__ x, const f16* __restrict__ wfrag,
    const float* __restrict__ noise,
    float* __restrict__ out_w, float* __restrict__ out_idx,
    float* __restrict__ out_logits, float* __restrict__ out_probs)
{
    __shared__ char smem[49152];
    const int tid = threadIdx.x;
    const int l   = tid & 63;
    const int w   = tid >> 6;      // wave 0..3; wave tile = 64 rows x cols [w*32, w*32+32)
    const int row0 = blockIdx.x * BM;

    f32x16 acc1[2], acc2[2];
    #pragma unroll
    for (int m = 0; m < 2; ++m)
        #pragma unroll
        for (int r = 0; r < 16; ++r) { acc1[m][r] = 0.0f; acc2[m][r] = 0.0f; }

    // --- A staging: wave w owns blob (m = w>>1, s = w&1); slot u = lane ---
    const int sw_m = w >> 1;
    const int sw_s = w & 1;
    const int sr   = sw_m * 32 + (l & 31);        // row 0..63
    const int sk   = sw_s * 16 + (l >> 5) * 8;    // k offset within 32
    const float* xrow = x + (size_t)(row0 + sr) * DDIM + sk;

    float4 xv0, xv1;
    auto stageA_load = [&](int i) {
        xv0 = *(const float4*)(xrow + i * KI);
        xv1 = *(const float4*)(xrow + i * KI + 4);
    };
    auto stageA_write = [&](int buf) {
        float xs[8] = {xv0.x, xv0.y, xv0.z, xv0.w, xv1.x, xv1.y, xv1.z, xv1.w};
        f16x8 hp, lp;
        #pragma unroll
        for (int j = 0; j < 8; ++j) {
            f16 h    = (f16)xs[j];
            float hf = (float)h;
            hp[j] = h;
            lp[j] = (f16)((xs[j] - hf) * 64.0f);
        }
        *(f16x8*)(smem + a_off(buf, 0, sw_m, sw_s) + l * 16) = hp;
        *(f16x8*)(smem + a_off(buf, 1, sw_m, sw_s) + l * 16) = lp;
    };
    // --- B staging: wave w stages its own col-quad f=w: (v,s) x {S = i*2+s} ---
    auto stageB = [&](int i, int buf) {
        #pragma unroll
        for (int v = 0; v < 2; ++v)
            #pragma unroll
            for (int s = 0; s < 2; ++s) {
                int S = i * 2 + s;
                const f16* src = wfrag + (size_t)(S * 4 + w) * 1024 + v * 512 + l * 8;
                gload_lds16(src, smem + b_off(buf, v, w, s));
            }
    };
    auto compute = [&](int buf) {
        #pragma unroll
        for (int s = 0; s < 2; ++s) {
            f16x8 Ah[2], Al[2], Bh, Bl;
            #pragma unroll
            for (int m = 0; m < 2; ++m) {
                Ah[m] = *(const f16x8*)(smem + a_off(buf, 0, m, s) + l * 16);
                Al[m] = *(const f16x8*)(smem + a_off(buf, 1, m, s) + l * 16);
            }
            Bh = *(const f16x8*)(smem + b_off(buf, 0, w, s) + l * 16);
            Bl = *(const f16x8*)(smem + b_off(buf, 1, w, s) + l * 16);
            #pragma unroll
            for (int m = 0; m < 2; ++m) {
                acc1[m] = __builtin_amdgcn_mfma_f32_32x32x16_f16(Ah[m], Bh, acc1[m], 0, 0, 0);
                acc2[m] = __builtin_amdgcn_mfma_f32_32x32x16_f16(Ah[m], Bl, acc2[m], 0, 0, 0);
                acc2[m] = __builtin_amdgcn_mfma_f32_32x32x16_f16(Al[m], Bh, acc2[m], 0, 0, 0);
            }
        }
    };

    // prologue
    stageA_load(0);
    stageB(0, 0);
    stageA_write(0);
    __syncthreads();

    for (int i = 0; i < NITER; ++i) {
        int buf = i & 1;
        bool more = (i + 1 < NITER);
        if (more) { stageA_load(i + 1); stageB(i + 1, buf ^ 1); }
        compute(buf);
        if (more) stageA_write(buf ^ 1);
        __syncthreads();
    }

    // ---- scatter C to lgf[64][132] (cols 0..63 gate, 64..127 noise) ----
    float* lgf = (float*)smem;
    #pragma unroll
    for (int m = 0; m < 2; ++m)
        #pragma unroll
        for (int r = 0; r < 16; ++r) {
            float cv  = fmaf(acc2[m][r], 0.015625f, acc1[m][r]);
            int row = m * 32 + (r & 3) + 8 * (r >> 2) + 4 * (l >> 5);
            int col = w * 32 + (l & 31);
            lgf[row * 132 + col] = cv;
        }
    __syncthreads();

    // ---- phase1: noise injection -> noisy logits in lgf[:,0..63] + out_logits ----
    {
        const int pr = l;            // row
        const int pc = w;            // expert chunk of 16
        const int n1 = row0 + pr;
        const float4* gl4 = (const float4*)(lgf + pr * 132 + pc * 16);
        const float4* nl4 = (const float4*)(lgf + pr * 132 + 64 + pc * 16);
        const float4* nz4 = (const float4*)(noise + (size_t)n1 * NE + pc * 16);
        float4* gw4 = (float4*)(lgf + pr * 132 + pc * 16);
        float4* ol4 = (float4*)(out_logits + (size_t)n1 * NE + pc * 16);
        #pragma unroll
        for (int q = 0; q < 4; ++q) {
            float4 G = gl4[q], NL = nl4[q], NZ = nz4[q];
            G.x += NZ.x * softplus_f(NL.x) * NSCALE;
            G.y += NZ.y * softplus_f(NL.y) * NSCALE;
            G.z += NZ.z * softplus_f(NL.z) * NSCALE;
            G.w += NZ.w * softplus_f(NL.w) * NSCALE;
            gw4[q] = G;
            ol4[q] = G;
        }
    }
    __syncthreads();

    // ---- phase2: per-row top-2 + softmax; 4 lanes/row x 64 rows ----
    {
        const int g2   = l >> 2;           // row within wave's 16-row group
        const int c    = l & 3;            // expert chunk of 16
        const int row2 = w * 16 + g2;
        const int n2   = row0 + row2;

        float mv[16];
        {
            const float4* mr = (const float4*)(lgf + row2 * 132 + c * 16);
            #pragma unroll
            for (int q = 0; q < 4; ++q) {
                float4 v = mr[q];
                mv[q*4+0] = v.x; mv[q*4+1] = v.y; mv[q*4+2] = v.z; mv[q*4+3] = v.w;
            }
        }
        float v0 = -INFINITY, v1 = -INFINITY;
        int i0 = 0, i1 = 0;
        #pragma unroll
        for (int j = 0; j < 16; ++j) {
            float v = mv[j]; int e = c * 16 + j;
            if (v > v0) { v1 = v0; i1 = i0; v0 = v; i0 = e; }
            else if (v > v1) { v1 = v; i1 = e; }
        }
        #pragma unroll
        for (int m = 1; m <= 2; m <<= 1) {
            float ov0 = __shfl_xor(v0, m), ov1 = __shfl_xor(v1, m);
            int   oi0 = __shfl_xor(i0, m), oi1 = __shfl_xor(i1, m);
            if (ov0 > v0) {
                bool keep = (v0 > ov1);
                v1 = keep ? v0 : ov1; i1 = keep ? i0 : oi1;
                v0 = ov0; i0 = oi0;
            } else if (ov0 > v1) {
                v1 = ov0; i1 = oi0;
            }
        }
        const int srcl = l & 60;
        v0 = __shfl(v0, srcl); i0 = __shfl(i0, srcl);
        v1 = __shfl(v1, srcl); i1 = __shfl(i1, srcl);

        float se = 0.0f;
        #pragma unroll
        for (int j = 0; j < 16; ++j) se += expf(mv[j] - v0);
        se += __shfl_xor(se, 1); se += __shfl_xor(se, 2);
        float inv_se = 1.0f / se;

        float t  = expf(v1 - v0);
        float w0 = 1.0f / (1.0f + t);
        float w1 = t * w0;

        float pr[16], wt[16];
        #pragma unroll
        for (int j = 0; j < 16; ++j) {
            int e = c * 16 + j;
            pr[j] = expf(mv[j] - v0) * inv_se;
            wt[j] = (e == i0) ? w0 : ((e == i1) ? w1 : 0.0f);
        }
        #pragma unroll
        for (int q = 0; q < 4; ++q) {
            *(float4*)(out_probs + (size_t)n2 * NE + c * 16 + q * 4) =
                make_float4(pr[q*4+0], pr[q*4+1], pr[q*4+2], pr[q*4+3]);
            *(float4*)(out_w + (size_t)n2 * NE + c * 16 + q * 4) =
                make_float4(wt[q*4+0], wt[q*4+1], wt[q*4+2], wt[q*4+3]);
        }
        if (c == 0) {
            *(float2*)(out_idx + (size_t)n2 * 2) = make_float2((float)i0, (float)i1);
        }
    }
}

extern "C" void kernel_launch(void* const* d_in, const int* in_sizes, int n_in,
                              void* d_out, int out_size, void* d_ws, size_t ws_size,
                              hipStream_t stream) {
    (void)in_sizes; (void)n_in; (void)ws_size; (void)out_size;
    const float* x     = (const float*)d_in[0];
    const float* Wg    = (const float*)d_in[1];
    const float* Wn    = (const float*)d_in[2];
    const float* noise = (const float*)d_in[3];
    float* out        = (float*)d_out;
    float* out_w      = out;
    float* out_idx    = out + (size_t)NROWS * NE;
    float* out_logits = out_idx + (size_t)NROWS * 2;
    float* out_probs  = out_logits + (size_t)NROWS * NE;
    f16* wfrag = (f16*)d_ws;   // 1 MB

    wprep_kernel<<<128, 256, 0, stream>>>(Wg, Wn, wfrag);
    gemm_gating<<<NROWS / BM, 256, 0, stream>>>(
        x, wfrag, noise, out_w, out_idx, out_logits, out_probs);
}

// Round 5
// 63.204 us; speedup vs baseline: 4.2000x; 1.2654x over previous
//
#include <hip/hip_runtime.h>
#include <math.h>

// LinearGating: B=4,S=4096,D=2048,E=64,K=2 -> N=16384 rows
// out (flat f32): [weights N*64][indices N*2 (as float)][logits N*64][probs N*64]
//
// fp16 split-3 MFMA GEMM: C[N x 128] = X[N x 2048] @ [Wg|Wn]
//   x = h + d, w = H + D;  acc1 += h*H ; acc2 += h*(D*2^6) + (d*2^6)*H
//   C = acc1 + acc2 * 2^-6
// R5: BM 64 -> 32 (grid 512 = 2 blocks/CU) to fix latency-bound 10% occupancy.

typedef _Float16 f16;
typedef f16  f16x8  __attribute__((ext_vector_type(8)));
typedef float f32x16 __attribute__((ext_vector_type(16)));

constexpr int NROWS = 16384;
constexpr int DDIM  = 2048;
constexpr int NE    = 64;
constexpr int BM    = 32;
constexpr int KI    = 32;            // k per iteration
constexpr int NITER = DDIM / KI;     // 64
constexpr float NSCALE = 1.0f / 4096.0f;

__device__ __forceinline__ float softplus_f(float x) {
    return fmaxf(x, 0.0f) + log1pf(expf(-fabsf(x)));
}

// LDS blob offsets (1KB blobs = 64 lanes x 16B, lane-linear)
// A: [0, 8K)    buf(2) x v(2) x s(2)
// B: [8K, 40K)  buf(2) x v(2) x f(4) x s(2)
__device__ __forceinline__ int a_off(int buf, int v, int s) {
    return ((buf * 2 + v) * 2 + s) * 1024;
}
__device__ __forceinline__ int b_off(int buf, int v, int f, int s) {
    return 8192 + (((buf * 2 + v) * 4 + f) * 2 + s) * 1024;
}

__device__ __forceinline__ void gload_lds16(const void* g, void* l) {
    __builtin_amdgcn_global_load_lds(
        (const __attribute__((address_space(1))) void*)g,
        (__attribute__((address_space(3))) void*)l, 16, 0, 0);
}

// ---------------- W prep: fragment-ordered fp16 {H, D*2^6} ----------------
// blob(S 0..127, f 0..3, v 0..1): lane l, elem j = Wcat[S*16+(l>>5)*8+j][f*32+(l&31)]
__global__ __launch_bounds__(256) void wprep_kernel(
    const float* __restrict__ Wg, const float* __restrict__ Wn,
    f16* __restrict__ ws)
{
    int t = blockIdx.x * 256 + threadIdx.x;    // 0..32767
    int S = t >> 8;
    int f = (t >> 6) & 3;
    int l = t & 63;
    int k0  = S * 16 + (l >> 5) * 8;
    int col = f * 32 + (l & 31);
    const float* src = (col < NE) ? (Wg + col) : (Wn + col - NE);
    f16x8 hp, lp;
    #pragma unroll
    for (int j = 0; j < 8; ++j) {
        float w  = src[(size_t)(k0 + j) * NE];
        f16 h    = (f16)w;
        float hf = (float)h;
        hp[j] = h;
        lp[j] = (f16)((w - hf) * 64.0f);
    }
    size_t base = (size_t)(S * 4 + f) * 1024;   // f16 units
    *(f16x8*)(ws + base + l * 8)       = hp;
    *(f16x8*)(ws + base + 512 + l * 8) = lp;
}

// ---------------- main fused kernel ----------------
__global__ __launch_bounds__(256, 2) void gemm_gating(
    const float* __restrict__ x, const f16* __restrict__ wfrag,
    const float* __restrict__ noise,
    float* __restrict__ out_w, float* __restrict__ out_idx,
    float* __restrict__ out_logits, float* __restrict__ out_probs)
{
    __shared__ char smem[40960];
    const int tid = threadIdx.x;
    const int l   = tid & 63;
    const int w   = tid >> 6;      // wave 0..3; wave tile = 32 rows x cols [w*32, w*32+32)
    const int row0 = blockIdx.x * BM;

    f32x16 acc1, acc2;
    #pragma unroll
    for (int r = 0; r < 16; ++r) { acc1[r] = 0.0f; acc2[r] = 0.0f; }

    // --- A staging: waves 0,1 own blob s=w; slot l: row=l&31, k-half=l>>5 ---
    const int sA   = w;                        // valid for w<2
    const int sr   = l & 31;
    const int kg   = sA * 2 + (l >> 5);        // 8-k group 0..3
    const float* xrow = x + (size_t)(row0 + sr) * DDIM + kg * 8;

    float4 xv0, xv1;
    auto stageA_load = [&](int i) {
        if (w < 2) {
            xv0 = *(const float4*)(xrow + i * KI);
            xv1 = *(const float4*)(xrow + i * KI + 4);
        }
    };
    auto stageA_write = [&](int buf) {
        if (w < 2) {
            float xs[8] = {xv0.x, xv0.y, xv0.z, xv0.w, xv1.x, xv1.y, xv1.z, xv1.w};
            f16x8 hp, lp;
            #pragma unroll
            for (int j = 0; j < 8; ++j) {
                f16 h    = (f16)xs[j];
                float hf = (float)h;
                hp[j] = h;
                lp[j] = (f16)((xs[j] - hf) * 64.0f);
            }
            *(f16x8*)(smem + a_off(buf, 0, sA) + l * 16) = hp;
            *(f16x8*)(smem + a_off(buf, 1, sA) + l * 16) = lp;
        }
    };
    // --- B staging: wave w stages its own col-quad f=w ---
    auto stageB = [&](int i, int buf) {
        #pragma unroll
        for (int v = 0; v < 2; ++v)
            #pragma unroll
            for (int s = 0; s < 2; ++s) {
                int S = i * 2 + s;
                const f16* src = wfrag + (size_t)(S * 4 + w) * 1024 + v * 512 + l * 8;
                gload_lds16(src, smem + b_off(buf, v, w, s));
            }
    };
    auto compute = [&](int buf) {
        #pragma unroll
        for (int s = 0; s < 2; ++s) {
            f16x8 Ah = *(const f16x8*)(smem + a_off(buf, 0, s) + l * 16);
            f16x8 Al = *(const f16x8*)(smem + a_off(buf, 1, s) + l * 16);
            f16x8 Bh = *(const f16x8*)(smem + b_off(buf, 0, w, s) + l * 16);
            f16x8 Bl = *(const f16x8*)(smem + b_off(buf, 1, w, s) + l * 16);
            acc1 = __builtin_amdgcn_mfma_f32_32x32x16_f16(Ah, Bh, acc1, 0, 0, 0);
            acc2 = __builtin_amdgcn_mfma_f32_32x32x16_f16(Ah, Bl, acc2, 0, 0, 0);
            acc2 = __builtin_amdgcn_mfma_f32_32x32x16_f16(Al, Bh, acc2, 0, 0, 0);
        }
    };

    // prologue
    stageA_load(0);
    stageB(0, 0);
    stageA_write(0);
    __syncthreads();

    for (int i = 0; i < NITER; ++i) {
        int buf = i & 1;
        bool more = (i + 1 < NITER);
        if (more) { stageA_load(i + 1); stageB(i + 1, buf ^ 1); }
        compute(buf);
        if (more) stageA_write(buf ^ 1);
        __syncthreads();
    }

    // ---- scatter C to lgf[32][132] (cols 0..63 gate, 64..127 noise) ----
    float* lgf = (float*)smem;
    #pragma unroll
    for (int r = 0; r < 16; ++r) {
        float cv = fmaf(acc2[r], 0.015625f, acc1[r]);
        int row = (r & 3) + 8 * (r >> 2) + 4 * (l >> 5);
        int col = w * 32 + (l & 31);
        lgf[row * 132 + col] = cv;
    }
    __syncthreads();

    // ---- phase1: noise injection -> noisy logits in lgf[:,0..63] + out_logits ----
    {
        const int pr = tid & 31;           // row
        const int c8 = tid >> 5;           // expert chunk of 8 (0..7)
        const int n1 = row0 + pr;
        const float4* gl4 = (const float4*)(lgf + pr * 132 + c8 * 8);
        const float4* nl4 = (const float4*)(lgf + pr * 132 + 64 + c8 * 8);
        const float4* nz4 = (const float4*)(noise + (size_t)n1 * NE + c8 * 8);
        float4* gw4 = (float4*)(lgf + pr * 132 + c8 * 8);
        float4* ol4 = (float4*)(out_logits + (size_t)n1 * NE + c8 * 8);
        #pragma unroll
        for (int q = 0; q < 2; ++q) {
            float4 G = gl4[q], NL = nl4[q], NZ = nz4[q];
            G.x += NZ.x * softplus_f(NL.x) * NSCALE;
            G.y += NZ.y * softplus_f(NL.y) * NSCALE;
            G.z += NZ.z * softplus_f(NL.z) * NSCALE;
            G.w += NZ.w * softplus_f(NL.w) * NSCALE;
            gw4[q] = G;
            ol4[q] = G;
        }
    }
    __syncthreads();

    // ---- phase2: per-row top-2 + softmax; 8 lanes/row x 32 rows ----
    {
        const int g2   = l >> 3;           // row within wave's 8-row group
        const int c    = l & 7;            // expert chunk of 8
        const int row2 = w * 8 + g2;
        const int n2   = row0 + row2;

        float mv[8];
        {
            const float4* mr = (const float4*)(lgf + row2 * 132 + c * 8);
            float4 m0 = mr[0], m1 = mr[1];
            mv[0]=m0.x; mv[1]=m0.y; mv[2]=m0.z; mv[3]=m0.w;
            mv[4]=m1.x; mv[5]=m1.y; mv[6]=m1.z; mv[7]=m1.w;
        }
        float v0 = -INFINITY, v1 = -INFINITY;
        int i0 = 0, i1 = 0;
        #pragma unroll
        for (int j = 0; j < 8; ++j) {
            float v = mv[j]; int e = c * 8 + j;
            if (v > v0) { v1 = v0; i1 = i0; v0 = v; i0 = e; }
            else if (v > v1) { v1 = v; i1 = e; }
        }
        #pragma unroll
        for (int m = 1; m <= 4; m <<= 1) {
            float ov0 = __shfl_xor(v0, m), ov1 = __shfl_xor(v1, m);
            int   oi0 = __shfl_xor(i0, m), oi1 = __shfl_xor(i1, m);
            if (ov0 > v0) {
                bool keep = (v0 > ov1);
                v1 = keep ? v0 : ov1; i1 = keep ? i0 : oi1;
                v0 = ov0; i0 = oi0;
            } else if (ov0 > v1) {
                v1 = ov0; i1 = oi0;
            }
        }
        const int srcl = l & 56;
        v0 = __shfl(v0, srcl); i0 = __shfl(i0, srcl);
        v1 = __shfl(v1, srcl); i1 = __shfl(i1, srcl);

        float se = 0.0f;
        #pragma unroll
        for (int j = 0; j < 8; ++j) se += expf(mv[j] - v0);
        se += __shfl_xor(se, 1); se += __shfl_xor(se, 2); se += __shfl_xor(se, 4);
        float inv_se = 1.0f / se;

        float t  = expf(v1 - v0);
        float w0 = 1.0f / (1.0f + t);
        float w1 = t * w0;

        float pr[8], wt[8];
        #pragma unroll
        for (int j = 0; j < 8; ++j) {
            int e = c * 8 + j;
            pr[j] = expf(mv[j] - v0) * inv_se;
            wt[j] = (e == i0) ? w0 : ((e == i1) ? w1 : 0.0f);
        }
        *(float4*)(out_probs + (size_t)n2 * NE + c * 8)     = make_float4(pr[0], pr[1], pr[2], pr[3]);
        *(float4*)(out_probs + (size_t)n2 * NE + c * 8 + 4) = make_float4(pr[4], pr[5], pr[6], pr[7]);
        *(float4*)(out_w + (size_t)n2 * NE + c * 8)         = make_float4(wt[0], wt[1], wt[2], wt[3]);
        *(float4*)(out_w + (size_t)n2 * NE + c * 8 + 4)     = make_float4(wt[4], wt[5], wt[6], wt[7]);
        if (c == 0) {
            *(float2*)(out_idx + (size_t)n2 * 2) = make_float2((float)i0, (float)i1);
        }
    }
}

extern "C" void kernel_launch(void* const* d_in, const int* in_sizes, int n_in,
                              void* d_out, int out_size, void* d_ws, size_t ws_size,
                              hipStream_t stream) {
    (void)in_sizes; (void)n_in; (void)ws_size; (void)out_size;
    const float* x     = (const float*)d_in[0];
    const float* Wg    = (const float*)d_in[1];
    const float* Wn    = (const float*)d_in[2];
    const float* noise = (const float*)d_in[3];
    float* out        = (float*)d_out;
    float* out_w      = out;
    float* out_idx    = out + (size_t)NROWS * NE;
    float* out_logits = out_idx + (size_t)NROWS * 2;
    float* out_probs  = out_logits + (size_t)NROWS * NE;
    f16* wfrag = (f16*)d_ws;   // 1 MB

    wprep_kernel<<<128, 256, 0, stream>>>(Wg, Wn, wfrag);
    gemm_gating<<<NROWS / BM, 256, 0, stream>>>(
        x, wfrag, noise, out_w, out_idx, out_logits, out_probs);
}